// Round 4
// baseline (265.108 us; speedup 1.0000x reference)
//
#include <hip/hip_runtime.h>

// Problem: B=2048 batches, N=64 members, D=256, H=16.
// out[b,n] = softmax_n( relu( (N*u[b,n,:] - sum_n u[b,n,:]) * item[b,:] @ W1 + b1 ) @ W2 )
// (b2 dropped: softmax is shift-invariant.)
//
// R3 lesson: no-LDS butterfly with acc[8][4]=128 VGPRs + 64 prefetch regs
// demanded ~230 regs; allocator clamped to 128 and spilled ~100MB scratch
// (WRITE_SIZE 97.8MB vs 0.5MB expected) -> 150us. Structure was never the
// problem; register pressure was.
//
// This version keeps the no-LDS / no-barrier butterfly structure with HALF
// the accumulator state and a pinned register budget:
//   lane (row=lane>>2, col2=lane&3): owns n in {row+16i} (4 rows),
//   d-float4-cols {col2+4t} (t=0..15), ALL 16 h.
//   acc[4][4] float4 = 64 VGPRs. d-reduction = 2-round butterfly (XOR 1,2).
//   u loads coalesced (16x64B/instr, sibling half-line = tile t+1 -> L1 hit).
//   W1 (16KB) read straight from global -> L1-resident broadcast gather.
//   amdgpu_waves_per_eu(2,2) pins codegen at 2 waves/EU (8 waves/CU, same
//   occupancy as all prior rounds) so the allocator targets 256 VGPRs and
//   has no reason to spill. DS ops: 0. Barriers: 0. LDS: 0.

static constexpr int NMEM = 64;
static constexpr int DDIM = 256;
static constexpr int NT   = 16;   // d-float4 tiles per lane: c = col2 + 4t

__device__ __forceinline__ void fma4(float4& a, float s, const float4& w) {
    a.x = fmaf(s, w.x, a.x); a.y = fmaf(s, w.y, a.y);
    a.z = fmaf(s, w.z, a.z); a.w = fmaf(s, w.w, a.w);
}
__device__ __forceinline__ float4 shfl4x(const float4& v, int m) {
    float4 r;
    r.x = __shfl_xor(v.x, m, 64); r.y = __shfl_xor(v.y, m, 64);
    r.z = __shfl_xor(v.z, m, 64); r.w = __shfl_xor(v.w, m, 64);
    return r;
}
__device__ __forceinline__ void add4(float4& a, const float4& b) {
    a.x += b.x; a.y += b.y; a.z += b.z; a.w += b.w;
}

__global__ __launch_bounds__(256)
__attribute__((amdgpu_waves_per_eu(2, 2)))
void attn_group_softmax(const float* __restrict__ u_g,     // [B,64,256]
                        const float* __restrict__ item_g,  // [B,256]
                        const float* __restrict__ W1,      // [256,16]
                        const float* __restrict__ b1,      // [16]
                        const float* __restrict__ W2,      // [16,1]
                        float* __restrict__ out)           // [B,64]
{
    const int tid  = threadIdx.x;
    const int w    = tid >> 6;                // wave id 0..3
    const int lane = tid & 63;
    const int b    = blockIdx.x * 4 + w;      // one batch per wave
    const int row  = lane >> 2;               // 0..15; owns n = row + 16i
    const int col2 = lane & 3;                // d-group; owns c = col2 + 4t

    const float4* ug4 = (const float4*)u_g + (size_t)b * (NMEM * DDIM / 4);
    const float4* ig4 = (const float4*)(item_g + (size_t)b * DDIM);
    const float4* w14 = (const float4*)W1;    // row d -> float4s 4d..4d+3 (16 h)

    // acc[i][g] = partial y'[row+16i][4g..4g+3] over lane's 64 d's
    float4 acc[4][4];
    #pragma unroll
    for (int i = 0; i < 4; ++i)
        #pragma unroll
        for (int g = 0; g < 4; ++g)
            acc[i][g] = make_float4(0.f, 0.f, 0.f, 0.f);

    // 1-deep double-buffered prefetch of the lane's u column + item slice
    float4 uc[4], un[4];
    #pragma unroll
    for (int i = 0; i < 4; ++i)
        uc[i] = ug4[(row + 16 * i) * (DDIM / 4) + col2];
    float4 itc = ig4[col2];
    float4 itn = itc;

    #pragma unroll
    for (int t = 0; t < NT; ++t) {
        if (t + 1 < NT) {
            const int cn = col2 + 4 * (t + 1);
            #pragma unroll
            for (int i = 0; i < 4; ++i)
                un[i] = ug4[(row + 16 * i) * (DDIM / 4) + cn];
            itn = ig4[cn];
        }
        const int rb = (col2 + 4 * t) * 4;    // first W1 row of this float4-col
        #pragma unroll
        for (int j = 0; j < 4; ++j) {
            const float4 wr0 = w14[(rb + j) * 4 + 0];
            const float4 wr1 = w14[(rb + j) * 4 + 1];
            const float4 wr2 = w14[(rb + j) * 4 + 2];
            const float4 wr3 = w14[(rb + j) * 4 + 3];
            const float itj = (j == 0) ? itc.x : (j == 1) ? itc.y
                            : (j == 2) ? itc.z : itc.w;
            #pragma unroll
            for (int i = 0; i < 4; ++i) {
                const float uj = (j == 0) ? uc[i].x : (j == 1) ? uc[i].y
                               : (j == 2) ? uc[i].z : uc[i].w;
                const float s = uj * itj;     // fold item at use
                fma4(acc[i][0], s, wr0);
                fma4(acc[i][1], s, wr1);
                fma4(acc[i][2], s, wr2);
                fma4(acc[i][3], s, wr3);
            }
        }
        if (t + 1 < NT) {
            #pragma unroll
            for (int i = 0; i < 4; ++i) uc[i] = un[i];
            itc = itn;
        }
    }

    // ---- d-reduction: butterfly over the 4 col2-lanes (masks 1,2) ----
    // afterwards acc = FULL y'[row+16i][h], replicated across col2.
    #pragma unroll
    for (int m = 1; m <= 2; m <<= 1)
        #pragma unroll
        for (int i = 0; i < 4; ++i)
            #pragma unroll
            for (int g = 0; g < 4; ++g)
                add4(acc[i][g], shfl4x(acc[i][g], m));

    // ---- tt[h] = sum over all 64 n of y'[n,h] ----
    // local sum over the lane's 4 n, then butterfly across rows (masks 4..32;
    // those partners share col2, so no double-count of the replication).
    float4 tt[4];
    #pragma unroll
    for (int g = 0; g < 4; ++g) {
        tt[g] = acc[0][g];
        #pragma unroll
        for (int i = 1; i < 4; ++i) add4(tt[g], acc[i][g]);
        #pragma unroll
        for (int m = 4; m <= 32; m <<= 1) add4(tt[g], shfl4x(tt[g], m));
    }

    const float4* b14 = (const float4*)b1;
    const float4* w24 = (const float4*)W2;
    float4 bt[4], w2v[4];
    #pragma unroll
    for (int g = 0; g < 4; ++g) {
        const float4 bb = b14[g];
        bt[g]  = make_float4(bb.x - tt[g].x, bb.y - tt[g].y,
                             bb.z - tt[g].z, bb.w - tt[g].w);
        w2v[g] = w24[g];
    }

    // ---- logits for the lane's 4 n's (replicated across col2) ----
    float lp[4];
    #pragma unroll
    for (int i = 0; i < 4; ++i) {
        float p = 0.f;
        #pragma unroll
        for (int g = 0; g < 4; ++g) {
            const float zx = fmaxf(fmaf(64.f, acc[i][g].x, bt[g].x), 0.f);
            const float zy = fmaxf(fmaf(64.f, acc[i][g].y, bt[g].y), 0.f);
            const float zz = fmaxf(fmaf(64.f, acc[i][g].z, bt[g].z), 0.f);
            const float zw = fmaxf(fmaf(64.f, acc[i][g].w, bt[g].w), 0.f);
            p += zx * w2v[g].x + zy * w2v[g].y + zz * w2v[g].z + zw * w2v[g].w;
        }
        lp[i] = p;
    }

    // ---- softmax over 64 n (4 local + butterfly over rows: masks 4..32) ----
    float mx = fmaxf(fmaxf(lp[0], lp[1]), fmaxf(lp[2], lp[3]));
    #pragma unroll
    for (int m = 4; m <= 32; m <<= 1) mx = fmaxf(mx, __shfl_xor(mx, m, 64));
    float e[4], s = 0.f;
    #pragma unroll
    for (int i = 0; i < 4; ++i) { e[i] = __expf(lp[i] - mx); s += e[i]; }
    #pragma unroll
    for (int m = 4; m <= 32; m <<= 1) s += __shfl_xor(s, m, 64);
    const float inv = 1.0f / s;

    // lane writes n = row + 16*col2 -> value e[col2] (compile-time select
    // chain -> no runtime-indexed register array -> no scratch). 64 lanes
    // cover batch b's 256B output block in one permuted coalesced store.
    float ev = e[0];
    ev = (col2 == 1) ? e[1] : ev;
    ev = (col2 == 2) ? e[2] : ev;
    ev = (col2 == 3) ? e[3] : ev;
    out[(size_t)b * NMEM + row + 16 * col2] = ev * inv;
}

extern "C" void kernel_launch(void* const* d_in, const int* in_sizes, int n_in,
                              void* d_out, int out_size, void* d_ws, size_t ws_size,
                              hipStream_t stream) {
    const float* u    = (const float*)d_in[0];  // members_embeds [2048,64,256]
    const float* item = (const float*)d_in[1];  // item_embeds   [2048,256]
    const float* W1   = (const float*)d_in[2];  // [256,16]
    const float* b1   = (const float*)d_in[3];  // [16]
    const float* W2   = (const float*)d_in[4];  // [16,1]
    // d_in[5] = b2: dropped (softmax shift-invariant)
    (void)in_sizes; (void)n_in; (void)out_size; (void)d_ws; (void)ws_size;

    attn_group_softmax<<<512, 256, 0, stream>>>(u, item, W1, b1, W2, (float*)d_out);
}

// Round 5
// 259.012 us; speedup vs baseline: 1.0235x; 1.0235x over previous
//
#include <hip/hip_runtime.h>

// Problem: B=2048 batches, N=64 members, D=256, H=16.
// out[b,n] = softmax_n( relu( (N*u[b,n,:] - sum_n u[b,n,:]) * item[b,:] @ W1 + b1 ) @ W2 )
// (b2 dropped: softmax is shift-invariant.)
//
// R3/R4 lesson: the backend clamps this kernel at 128 VGPRs no matter what
// occupancy hints are given, and spills the excess (R3: 97MB, R4: 37MB of
// scratch). The excess came from FULLY UNROLLING the 16-iteration d-tile
// loop: the scheduler hoists W1/u loads across iterations, blowing live
// ranges past acc+prefetch. Fix: runtime t-loop (#pragma unroll 1) so
// hoisting across iterations is impossible, and no u double-buffer (prefetch
// depth was twice proven non-binding). Live set ~115 VGPRs < 128 clamp.
//
// Structure (no LDS, no barriers, d lane-local -- T12 swapped-operand idea):
//   lane (row=lane>>2, col2=lane&3): owns n in {row+16i} (4 rows),
//   d-float4-cols {col2+4t} (t=0..15), ALL 16 h.
//   acc[4][4] float4 = 64 VGPRs = partial y'[4n][16h] over lane's 64 d's.
//   d-reduction = 2-round __shfl_xor butterfly (masks 1,2).
//   u loads coalesced (16x64B segments/instr); W1 read from global
//   (16KB, L1/L2-resident broadcast); DS ops: 0; barriers: 0; LDS: 0.

static constexpr int NMEM = 64;
static constexpr int DDIM = 256;
static constexpr int NT   = 16;   // d-float4 tiles per lane: c = col2 + 4t

__device__ __forceinline__ void fma4(float4& a, float s, const float4& w) {
    a.x = fmaf(s, w.x, a.x); a.y = fmaf(s, w.y, a.y);
    a.z = fmaf(s, w.z, a.z); a.w = fmaf(s, w.w, a.w);
}
__device__ __forceinline__ float4 shfl4x(const float4& v, int m) {
    float4 r;
    r.x = __shfl_xor(v.x, m, 64); r.y = __shfl_xor(v.y, m, 64);
    r.z = __shfl_xor(v.z, m, 64); r.w = __shfl_xor(v.w, m, 64);
    return r;
}
__device__ __forceinline__ void add4(float4& a, const float4& b) {
    a.x += b.x; a.y += b.y; a.z += b.z; a.w += b.w;
}

__global__ __launch_bounds__(256, 2)
void attn_group_softmax(const float* __restrict__ u_g,     // [B,64,256]
                        const float* __restrict__ item_g,  // [B,256]
                        const float* __restrict__ W1,      // [256,16]
                        const float* __restrict__ b1,      // [16]
                        const float* __restrict__ W2,      // [16,1]
                        float* __restrict__ out)           // [B,64]
{
    const int tid  = threadIdx.x;
    const int w    = tid >> 6;                // wave id 0..3
    const int lane = tid & 63;
    const int b    = blockIdx.x * 4 + w;      // one batch per wave
    const int row  = lane >> 2;               // 0..15; owns n = row + 16i
    const int col2 = lane & 3;                // d-group; owns c = col2 + 4t

    // walking pointers (advance per tile; no big immediate offsets needed)
    const float4* up = (const float4*)u_g + (size_t)b * (NMEM * DDIM / 4)
                     + row * (DDIM / 4) + col2;              // += 4 per tile
    const float4* ip = (const float4*)(item_g + (size_t)b * DDIM) + col2; // += 4
    const float4* wp = (const float4*)W1 + col2 * 16;        // += 64 per tile

    // acc[i][g] = partial y'[row+16i][4g..4g+3] over lane's 64 d's
    float4 acc[4][4];
    #pragma unroll
    for (int i = 0; i < 4; ++i)
        #pragma unroll
        for (int g = 0; g < 4; ++g)
            acc[i][g] = make_float4(0.f, 0.f, 0.f, 0.f);

    #pragma unroll 1            // RUNTIME loop: forbid cross-iteration hoisting
    for (int t = 0; t < NT; ++t) {
        const float4 itc = *ip;
        const float4 u0 = up[0];                 // rows row, row+16, row+32, row+48
        const float4 u1 = up[16 * (DDIM / 4)];
        const float4 u2 = up[32 * (DDIM / 4)];
        const float4 u3 = up[48 * (DDIM / 4)];
        #pragma unroll
        for (int j = 0; j < 4; ++j) {            // d = 4*(col2+4t) + j
            const float4 wr0 = wp[4 * j + 0];    // W1[d, 0..3]
            const float4 wr1 = wp[4 * j + 1];    // W1[d, 4..7]
            const float4 wr2 = wp[4 * j + 2];    // W1[d, 8..11]
            const float4 wr3 = wp[4 * j + 3];    // W1[d,12..15]
            const float itj = (j == 0) ? itc.x : (j == 1) ? itc.y
                            : (j == 2) ? itc.z : itc.w;
            const float s0 = ((j == 0) ? u0.x : (j == 1) ? u0.y
                            : (j == 2) ? u0.z : u0.w) * itj;
            const float s1 = ((j == 0) ? u1.x : (j == 1) ? u1.y
                            : (j == 2) ? u1.z : u1.w) * itj;
            const float s2 = ((j == 0) ? u2.x : (j == 1) ? u2.y
                            : (j == 2) ? u2.z : u2.w) * itj;
            const float s3 = ((j == 0) ? u3.x : (j == 1) ? u3.y
                            : (j == 2) ? u3.z : u3.w) * itj;
            fma4(acc[0][0], s0, wr0); fma4(acc[0][1], s0, wr1);
            fma4(acc[0][2], s0, wr2); fma4(acc[0][3], s0, wr3);
            fma4(acc[1][0], s1, wr0); fma4(acc[1][1], s1, wr1);
            fma4(acc[1][2], s1, wr2); fma4(acc[1][3], s1, wr3);
            fma4(acc[2][0], s2, wr0); fma4(acc[2][1], s2, wr1);
            fma4(acc[2][2], s2, wr2); fma4(acc[2][3], s2, wr3);
            fma4(acc[3][0], s3, wr0); fma4(acc[3][1], s3, wr1);
            fma4(acc[3][2], s3, wr2); fma4(acc[3][3], s3, wr3);
        }
        up += 4; ip += 4; wp += 64;
    }

    // ---- d-reduction: butterfly over the 4 col2-lanes (masks 1,2) ----
    // afterwards acc = FULL y'[row+16i][h], replicated across col2.
    #pragma unroll
    for (int m = 1; m <= 2; m <<= 1)
        #pragma unroll
        for (int i = 0; i < 4; ++i)
            #pragma unroll
            for (int g = 0; g < 4; ++g)
                add4(acc[i][g], shfl4x(acc[i][g], m));

    // ---- tt[h] = sum over all 64 n of y'[n,h] ----
    // local sum over the lane's 4 n, then butterfly across rows (masks 4..32;
    // partners share col2, so the col2-replication is not double-counted).
    float4 tt[4];
    #pragma unroll
    for (int g = 0; g < 4; ++g) {
        tt[g] = acc[0][g];
        #pragma unroll
        for (int i = 1; i < 4; ++i) add4(tt[g], acc[i][g]);
        #pragma unroll
        for (int m = 4; m <= 32; m <<= 1) add4(tt[g], shfl4x(tt[g], m));
    }

    const float4* b14 = (const float4*)b1;
    const float4* w24 = (const float4*)W2;
    float4 bt[4], w2v[4];
    #pragma unroll
    for (int g = 0; g < 4; ++g) {
        const float4 bb = b14[g];
        bt[g]  = make_float4(bb.x - tt[g].x, bb.y - tt[g].y,
                             bb.z - tt[g].z, bb.w - tt[g].w);
        w2v[g] = w24[g];
    }

    // ---- logits for the lane's 4 n's (replicated across col2) ----
    float lp[4];
    #pragma unroll
    for (int i = 0; i < 4; ++i) {
        float p = 0.f;
        #pragma unroll
        for (int g = 0; g < 4; ++g) {
            const float zx = fmaxf(fmaf(64.f, acc[i][g].x, bt[g].x), 0.f);
            const float zy = fmaxf(fmaf(64.f, acc[i][g].y, bt[g].y), 0.f);
            const float zz = fmaxf(fmaf(64.f, acc[i][g].z, bt[g].z), 0.f);
            const float zw = fmaxf(fmaf(64.f, acc[i][g].w, bt[g].w), 0.f);
            p += zx * w2v[g].x + zy * w2v[g].y + zz * w2v[g].z + zw * w2v[g].w;
        }
        lp[i] = p;
    }

    // ---- softmax over 64 n (4 local + butterfly over rows: masks 4..32) ----
    float mx = fmaxf(fmaxf(lp[0], lp[1]), fmaxf(lp[2], lp[3]));
    #pragma unroll
    for (int m = 4; m <= 32; m <<= 1) mx = fmaxf(mx, __shfl_xor(mx, m, 64));
    float e[4], s = 0.f;
    #pragma unroll
    for (int i = 0; i < 4; ++i) { e[i] = __expf(lp[i] - mx); s += e[i]; }
    #pragma unroll
    for (int m = 4; m <= 32; m <<= 1) s += __shfl_xor(s, m, 64);
    const float inv = 1.0f / s;

    // lane writes n = row + 16*col2 -> value e[col2] (compile-time select
    // chain -> no runtime-indexed register array -> no scratch). 64 lanes
    // cover batch b's 256B output block in one permuted coalesced store.
    float ev = e[0];
    ev = (col2 == 1) ? e[1] : ev;
    ev = (col2 == 2) ? e[2] : ev;
    ev = (col2 == 3) ? e[3] : ev;
    out[(size_t)b * NMEM + row + 16 * col2] = ev * inv;
}

extern "C" void kernel_launch(void* const* d_in, const int* in_sizes, int n_in,
                              void* d_out, int out_size, void* d_ws, size_t ws_size,
                              hipStream_t stream) {
    const float* u    = (const float*)d_in[0];  // members_embeds [2048,64,256]
    const float* item = (const float*)d_in[1];  // item_embeds   [2048,256]
    const float* W1   = (const float*)d_in[2];  // [256,16]
    const float* b1   = (const float*)d_in[3];  // [16]
    const float* W2   = (const float*)d_in[4];  // [16,1]
    // d_in[5] = b2: dropped (softmax shift-invariant)
    (void)in_sizes; (void)n_in; (void)out_size; (void)d_ws; (void)ws_size;

    attn_group_softmax<<<512, 256, 0, stream>>>(u, item, W1, b1, W2, (float*)d_out);
}

// Round 6
// 235.863 us; speedup vs baseline: 1.1240x; 1.0981x over previous
//
#include <hip/hip_runtime.h>

// Problem: B=2048 batches, N=64 members, D=256, H=16.
// out[b,n] = softmax_n( relu( (N*u[b,n,:] - sum_n u[b,n,:]) * item[b,:] @ W1 + b1 ) @ W2 )
// (b2 dropped: softmax is shift-invariant.)
//
// R3-R5 lesson: the no-LDS register-butterfly dataflow is compiler-hostile
// (fully unrolled -> 128-VGPR clamp + 40-100MB spill; unroll-1 -> 56-VGPR
// serialization of 21 loads/iter -> 116us latency-bound). Abandoned.
//
// This version = R0's LDS structure (empirically ~62us) minus its two real
// costs, per the guide's proven ladder:
//  * global_load_lds staging (async DMA: no staging VGPRs, no ds_writes,
//    no global->reg->LDS roundtrip). Loop's ONLY VMEM = 8 loads per tile.
//  * counted-vmcnt 2-deep tile pipeline, ZERO barriers in the loop (tiles
//    are wave-private; vmcnt(8) at tile top keeps next tile's loads in
//    flight -- never drains to 0 mid-loop). T4 from the technique catalog.
//  * global_load_lds writes LDS linearly, so conflict-freedom comes from
//    pre-swizzling the GLOBAL source column (sco = (lane&7)^(lane>>3)) and
//    XOR-ing the read column (d4 ^ (n0&7)): 2-way read alias only (free).
//  * item[b] lives in 4 regs/lane (lane holds item[4l..4l+3]); per-d4 the
//    uniform scalar is fetched with v_readlane (SALU, no DS, no vmcnt).
// LDS: W1 16KB (shared) + 4 waves x 2 x 8KB tiles = 80KB -> 2 blocks/CU.

static constexpr int NMEM = 64;
static constexpr int DDIM = 256;
static constexpr int NTILE = 8;   // 8 d-tiles of width 32

__device__ __forceinline__ void fma4(float4& a, float s, const float4& w) {
    a.x = fmaf(s, w.x, a.x); a.y = fmaf(s, w.y, a.y);
    a.z = fmaf(s, w.z, a.z); a.w = fmaf(s, w.w, a.w);
}
__device__ __forceinline__ float rdlane(float v, int srclane) {
    return __int_as_float(__builtin_amdgcn_readlane(__float_as_int(v), srclane));
}

__global__ __launch_bounds__(256, 2)
void attn_group_softmax(const float* __restrict__ u_g,     // [B,64,256]
                        const float* __restrict__ item_g,  // [B,256]
                        const float* __restrict__ W1,      // [256,16]
                        const float* __restrict__ b1,      // [16]
                        const float* __restrict__ W2,      // [16,1]
                        float* __restrict__ out)           // [B,64]
{
    __shared__ float w1s[DDIM * 16];        // 16 KB, shared by all 4 waves
    __shared__ float tiles[4][2][NMEM * 32]; // 4 waves x 2 bufs x 8KB

    const int tid  = threadIdx.x;
    const int w    = tid >> 6;              // wave id 0..3
    const int lane = tid & 63;
    const int b    = blockIdx.x * 4 + w;    // one batch per wave

    // ---- stage W1 (block-wide, 4096 floats) + item (4 regs/lane) ----
    {
        const float4* src = (const float4*)W1;
        float4* dst = (float4*)w1s;
        #pragma unroll
        for (int i = 0; i < 4; ++i) dst[tid + 256 * i] = src[tid + 256 * i];
    }
    const float4 it4 = ((const float4*)(item_g + (size_t)b * DDIM))[lane];
    __syncthreads();   // the ONLY barrier (w1s visibility; drains prologue vmem)

    const int q    = lane & 3;              // h-group: h = 4q..4q+3
    const int n0   = lane >> 2;             // 0..15; owns n = n0 + 16k
    const int pk   = n0 & 7;                // read swizzle key
    const int sco  = (lane & 7) ^ (lane >> 3);  // pre-swizzled global col

    // per-lane global float4 base for staging: row (lane>>3), swizzled col
    const float4* gstage = (const float4*)u_g + (size_t)b * (NMEM * DDIM / 4)
                         + (lane >> 3) * (DDIM / 4) + sco;
    float* const tb0 = &tiles[w][0][0];
    float* const tb1 = &tiles[w][1][0];
    const float4* w1s4 = (const float4*)w1s;

    // stage tile t (8 async 1KB chunks; LDS dest wave-uniform, linear)
    auto stage = [&](int t, float* lb) {
        const float4* g = gstage + t * 8;   // +8 float4 per tile
        #pragma unroll
        for (int k = 0; k < 8; ++k)
            __builtin_amdgcn_global_load_lds(
                (const __attribute__((address_space(1))) void*)(g + k * 512),
                (__attribute__((address_space(3))) void*)(lb + k * 256),
                16, 0, 0);
    };

    float4 acc0 = make_float4(0.f, 0.f, 0.f, 0.f);
    float4 acc1 = acc0, acc2 = acc0, acc3 = acc0;

    auto compute_tile = [&](int t, const float* lb) {
        const float4* lb4 = (const float4*)lb;
        #pragma unroll
        for (int d4 = 0; d4 < 8; ++d4) {
            // uniform item scalars for d = t*32 + d4*4 + j  (lane t*8+d4)
            const int f = t * 8 + d4;
            const float itx = rdlane(it4.x, f);
            const float ity = rdlane(it4.y, f);
            const float itz = rdlane(it4.z, f);
            const float itw = rdlane(it4.w, f);
            const int p = d4 ^ pk;          // swizzled read column
            const float4 ua = lb4[(n0     ) * 8 + p];
            const float4 ub = lb4[(n0 + 16) * 8 + p];
            const float4 uc = lb4[(n0 + 32) * 8 + p];
            const float4 ud = lb4[(n0 + 48) * 8 + p];
            const int wb = (t * 32 + d4 * 4) * 4 + q;
            const float4 w0  = w1s4[wb];
            const float4 w1r = w1s4[wb + 4];
            const float4 w2r = w1s4[wb + 8];
            const float4 w3r = w1s4[wb + 12];
            {   const float s0 = ua.x*itx, s1 = ua.y*ity, s2 = ua.z*itz, s3 = ua.w*itw;
                fma4(acc0, s0, w0); fma4(acc0, s1, w1r);
                fma4(acc0, s2, w2r); fma4(acc0, s3, w3r); }
            {   const float s0 = ub.x*itx, s1 = ub.y*ity, s2 = ub.z*itz, s3 = ub.w*itw;
                fma4(acc1, s0, w0); fma4(acc1, s1, w1r);
                fma4(acc1, s2, w2r); fma4(acc1, s3, w3r); }
            {   const float s0 = uc.x*itx, s1 = uc.y*ity, s2 = uc.z*itz, s3 = uc.w*itw;
                fma4(acc2, s0, w0); fma4(acc2, s1, w1r);
                fma4(acc2, s2, w2r); fma4(acc2, s3, w3r); }
            {   const float s0 = ud.x*itx, s1 = ud.y*ity, s2 = ud.z*itz, s3 = ud.w*itw;
                fma4(acc3, s0, w0); fma4(acc3, s1, w1r);
                fma4(acc3, s2, w2r); fma4(acc3, s3, w3r); }
        }
    };

    // ---- pipelined K-loop: 2 tile-groups in flight, vmcnt(8) at tile top ----
    stage(0, tb0);
    stage(1, tb1);
    #pragma unroll 1
    for (int t = 0; t < 7; ++t) {
        asm volatile("s_waitcnt vmcnt(8)" ::: "memory");   // tile t landed
        float* lb = (t & 1) ? tb1 : tb0;
        compute_tile(t, lb);
        asm volatile("s_waitcnt lgkmcnt(0)" ::: "memory"); // reads done: WAR-safe
        if (t < 6) stage(t + 2, lb);                       // t+2 has same parity
    }
    asm volatile("s_waitcnt vmcnt(0)" ::: "memory");
    compute_tile(7, tb1);

    // ---- epilogue (registers + shuffles only; identical to the R0 kernel) ----
    float4 tt;
    tt.x = acc0.x + acc1.x + acc2.x + acc3.x;
    tt.y = acc0.y + acc1.y + acc2.y + acc3.y;
    tt.z = acc0.z + acc1.z + acc2.z + acc3.z;
    tt.w = acc0.w + acc1.w + acc2.w + acc3.w;
    #pragma unroll
    for (int off = 4; off <= 32; off <<= 1) {
        tt.x += __shfl_xor(tt.x, off, 64);
        tt.y += __shfl_xor(tt.y, off, 64);
        tt.z += __shfl_xor(tt.z, off, 64);
        tt.w += __shfl_xor(tt.w, off, 64);
    }

    const float4 b1v = ((const float4*)b1)[q];
    const float4 w2v = ((const float4*)W2)[q];

    auto logit_part = [&](const float4& a) -> float {
        const float zx = fmaxf(fmaf(64.f, a.x, b1v.x - tt.x), 0.f);
        const float zy = fmaxf(fmaf(64.f, a.y, b1v.y - tt.y), 0.f);
        const float zz = fmaxf(fmaf(64.f, a.z, b1v.z - tt.z), 0.f);
        const float zw = fmaxf(fmaf(64.f, a.w, b1v.w - tt.w), 0.f);
        return zx * w2v.x + zy * w2v.y + zz * w2v.z + zw * w2v.w;
    };

    float p0 = logit_part(acc0);
    float p1 = logit_part(acc1);
    float p2 = logit_part(acc2);
    float p3 = logit_part(acc3);
    p0 += __shfl_xor(p0, 1, 64); p0 += __shfl_xor(p0, 2, 64);
    p1 += __shfl_xor(p1, 1, 64); p1 += __shfl_xor(p1, 2, 64);
    p2 += __shfl_xor(p2, 1, 64); p2 += __shfl_xor(p2, 2, 64);
    p3 += __shfl_xor(p3, 1, 64); p3 += __shfl_xor(p3, 2, 64);

    float m = fmaxf(fmaxf(p0, p1), fmaxf(p2, p3));
    #pragma unroll
    for (int off = 4; off <= 32; off <<= 1) m = fmaxf(m, __shfl_xor(m, off, 64));
    const float e0 = __expf(p0 - m);
    const float e1 = __expf(p1 - m);
    const float e2 = __expf(p2 - m);
    const float e3 = __expf(p3 - m);
    float s = e0 + e1 + e2 + e3;
    #pragma unroll
    for (int off = 4; off <= 32; off <<= 1) s += __shfl_xor(s, off, 64);
    const float inv = 1.0f / s;

    if (q == 0) {
        float* ob = out + (size_t)b * NMEM + n0;
        ob[0]  = e0 * inv;
        ob[16] = e1 * inv;
        ob[32] = e2 * inv;
        ob[48] = e3 * inv;
    }
}

extern "C" void kernel_launch(void* const* d_in, const int* in_sizes, int n_in,
                              void* d_out, int out_size, void* d_ws, size_t ws_size,
                              hipStream_t stream) {
    const float* u    = (const float*)d_in[0];  // members_embeds [2048,64,256]
    const float* item = (const float*)d_in[1];  // item_embeds   [2048,256]
    const float* W1   = (const float*)d_in[2];  // [256,16]
    const float* b1   = (const float*)d_in[3];  // [16]
    const float* W2   = (const float*)d_in[4];  // [16,1]
    // d_in[5] = b2: dropped (softmax shift-invariant)
    (void)in_sizes; (void)n_in; (void)out_size; (void)d_ws; (void)ws_size;

    attn_group_softmax<<<512, 256, 0, stream>>>(u, item, W1, b1, W2, (float*)d_out);
}